// Round 13
// baseline (153.745 us; speedup 1.0000x reference)
//
#include <hip/hip_runtime.h>
#include <stdint.h>

#define PRO_NUM 64
#define TERM_NUM 512
#define MAX_LEN 1024
#define HID 256

typedef _Float16 f16x8 __attribute__((ext_vector_type(8)));
typedef float f32x4 __attribute__((ext_vector_type(4)));

__device__ __forceinline__ f16x8 cvt8(const float* __restrict__ s) {
  float4 a = *(const float4*)s;
  float4 b = *(const float4*)(s + 4);
  f16x8 r = {(_Float16)a.x, (_Float16)a.y, (_Float16)a.z, (_Float16)a.w,
             (_Float16)b.x, (_Float16)b.y, (_Float16)b.z, (_Float16)b.w};
  return r;
}

// async global->LDS, 16B per lane; lds base must be wave-uniform (HW adds lane*16)
__device__ __forceinline__ void gll16(const void* g, void* l) {
  __builtin_amdgcn_global_load_lds(
      (const __attribute__((address_space(1))) uint32_t*)g,
      (__attribute__((address_space(3))) uint32_t*)l, 16, 0, 0);
}

// K1: pro f32 -> (a) img: per-(p,64-l-chunk) 32KB swizzled LDS images of pro_h
//                (byte(l,h8) = l*512 + ((h8*16) ^ ((l&7)<<4)), h8 = h/8)
//                (b) fragT: PV B-operand fragments.
__global__ __launch_bounds__(256) void k_prep(const float* __restrict__ pro,
                                              char* __restrict__ img,
                                              f16x8* __restrict__ fragT) {
  __shared__ _Float16 ldsA[64][264];
  const int p = blockIdx.y;
  const int lc = blockIdx.x;
  const int tid = threadIdx.x;

  const float* src = pro + ((size_t)p * MAX_LEN + lc * 64) * HID;
  #pragma unroll
  for (int j = 0; j < 16; ++j) {
    int idx = j * 1024 + tid * 4;
    int l = idx >> 8, h = idx & 255;
    float4 v = *(const float4*)(src + idx);
    ldsA[l][h + 0] = (_Float16)v.x;
    ldsA[l][h + 1] = (_Float16)v.y;
    ldsA[l][h + 2] = (_Float16)v.z;
    ldsA[l][h + 3] = (_Float16)v.w;
  }
  __syncthreads();

  // (a) swizzled image
  {
    char* dst = img + ((size_t)(p * 16 + lc)) * 32768;
    const int h8 = tid & 31;
    const int l0 = tid >> 5;  // 0..7
    #pragma unroll
    for (int j = 0; j < 8; ++j) {
      const int l = j * 8 + l0;
      f16x8 v = *(const f16x8*)&ldsA[l][h8 * 8];
      *(f16x8*)(dst + l * 512 + ((h8 * 16) ^ ((l & 7) << 4))) = v;
    }
  }

  // (b) fragT
  const int w = tid >> 6;
  const int lane = tid & 63;
  const int lr = lane & 15;
  const int lg = lane >> 4;
  #pragma unroll
  for (int hh = 0; hh < 4; ++hh) {
    const int H = w * 4 + hh;
    #pragma unroll
    for (int k2 = 0; k2 < 2; ++k2) {
      const int kc = lc * 2 + k2;
      const int lloc = k2 * 32 + lg * 8;
      f16x8 v;
      #pragma unroll
      for (int i = 0; i < 8; ++i) v[i] = ldsA[lloc + i][H * 16 + lr];
      fragT[((size_t)(p * 16 + H) * 32 + kc) * 64 + lane] = v;
    }
  }
}

// K2 (fused): block = (p, 32 terms), 4 waves. IDENTITY block mapping (no XCD-p
// clustering): per-block duration ~ len(p), so same-p blocks are spread across
// XCDs to balance len over the machine. Phase A: len-clipped chunk loop,
// double-buffered global_load_lds. Softmax -> P to LDS (f16 swizzled). Phase C: PV
// from LDS P + fragT (8-deep load batches). Finally: coalesced NT attn writeback,
// LDS-read clipped to live chunks, zero-fill tail.
__global__ __launch_bounds__(256) void k_fused(
    const float* __restrict__ term, const char* __restrict__ img,
    const f16x8* __restrict__ fragT, const int* __restrict__ lens,
    float* __restrict__ attn, float* __restrict__ out) {
  __shared__ __align__(16) char bufA[32768];  // chunk stage (even) / P rows 0-15
  __shared__ __align__(16) char bufB[32768];  // chunk stage (odd)  / P rows 16-31
  __shared__ float rmx[4][16];
  __shared__ float rsm[4][16];

  const int bid = blockIdx.x;
  const int p = bid >> 4;
  const int t0 = (bid & 15) * 32;

  const int tid = threadIdx.x;
  const int w = tid >> 6;
  const int lane = tid & 63;
  const int lr = lane & 15;
  const int lg = lane >> 4;
  const int len = lens[p];
  const int mw = w & 1;   // m-tile owned by this wave
  const int lh = w >> 1;  // l-half within each chunk
  const int nchunks = (len + 63) >> 6;  // 1..16, wave-uniform

  // A fragments (term rows t0+mw*16+lr)
  f16x8 af[8];
  {
    const float* trow = term + (size_t)(t0 + mw * 16 + lr) * HID + lg * 8;
    #pragma unroll
    for (int kk = 0; kk < 8; ++kk) af[kk] = cvt8(trow + kk * 32);
  }

  f32x4 acc[32];
  #pragma unroll
  for (int i = 0; i < 32; ++i) acc[i] = (f32x4){0.f, 0.f, 0.f, 0.f};

  const char* imgp = img + ((size_t)p * 16) * 32768 + w * 1024 + lane * 16;
  char* stA = bufA + w * 1024;
  char* stB = bufB + w * 1024;

  // prologue: stage chunk 0 (len >= 1 always)
  #pragma unroll
  for (int r = 0; r < 8; ++r) gll16(imgp + r * 4096, stA + r * 4096);
  __syncthreads();

  const int swk = (lr & 7) << 4;
  #pragma unroll
  for (int c = 0; c < 16; ++c) {
    if (c + 1 < nchunks) {  // stage next live chunk
      const char* src = imgp + (size_t)(c + 1) * 32768;
      char* dst = (c & 1) ? stA : stB;
      #pragma unroll
      for (int r = 0; r < 8; ++r) gll16(src + r * 4096, dst + r * 4096);
    }
    if (c < nchunks) {  // compute live chunk (wave-uniform)
      const char* cur = (c & 1) ? bufB : bufA;
      #pragma unroll
      for (int j = 0; j < 2; ++j) {
        const int lt = lh * 2 + j;
        const char* rowp = cur + (lt * 16 + lr) * 512;
        f16x8 bf[8];
        #pragma unroll
        for (int kk = 0; kk < 8; ++kk)
          bf[kk] = *(const f16x8*)(rowp + ((kk * 64 + lg * 16) ^ swk));
        #pragma unroll
        for (int kk = 0; kk < 8; ++kk)
          acc[c * 2 + j] =
              __builtin_amdgcn_mfma_f32_16x16x32_f16(af[kk], bf[kk], acc[c * 2 + j], 0, 0, 0);
      }
    }
    __syncthreads();  // uniform barrier every iteration
  }

  // ---------------- softmax ----------------
  float rmax[4] = {-INFINITY, -INFINITY, -INFINITY, -INFINITY};
  #pragma unroll
  for (int a = 0; a < 32; ++a) {
    const int l = (a >> 1) * 64 + lh * 32 + (a & 1) * 16 + lr;
    #pragma unroll
    for (int r = 0; r < 4; ++r) {
      float s = (l < len) ? acc[a][r] : -INFINITY;
      acc[a][r] = s;
      rmax[r] = fmaxf(rmax[r], s);
    }
  }
  #pragma unroll
  for (int m = 1; m < 16; m <<= 1) {
    #pragma unroll
    for (int r = 0; r < 4; ++r) rmax[r] = fmaxf(rmax[r], __shfl_xor(rmax[r], m));
  }
  if (lr == 0) {
    #pragma unroll
    for (int r = 0; r < 4; ++r) rmx[w][lg * 4 + r] = rmax[r];
  }
  __syncthreads();
  float fm[4];
  #pragma unroll
  for (int r = 0; r < 4; ++r) {
    const int rl = lg * 4 + r;
    fm[r] = fmaxf(rmx[mw][rl], rmx[2 + mw][rl]);
  }
  float rsum[4] = {0.f, 0.f, 0.f, 0.f};
  #pragma unroll
  for (int a = 0; a < 32; ++a) {
    #pragma unroll
    for (int r = 0; r < 4; ++r) {
      float e = __expf(acc[a][r] - fm[r]);  // masked -> 0
      acc[a][r] = e;
      rsum[r] += e;
    }
  }
  #pragma unroll
  for (int m = 1; m < 16; m <<= 1) {
    #pragma unroll
    for (int r = 0; r < 4; ++r) rsum[r] += __shfl_xor(rsum[r], m);
  }
  if (lr == 0) {
    #pragma unroll
    for (int r = 0; r < 4; ++r) rsm[w][lg * 4 + r] = rsum[r];
  }
  __syncthreads();
  float inv[4];
  #pragma unroll
  for (int r = 0; r < 4; ++r) {
    const int rl = lg * 4 + r;
    inv[r] = 1.0f / (rsm[mw][rl] + rsm[2 + mw][rl]);
  }

  // P -> LDS only (f16, col ^ ((row&7)<<3)); bufA rows 0-15, bufB rows 16-31
  {
    _Float16* pb = (_Float16*)(mw ? bufB : bufA);
    #pragma unroll
    for (int r = 0; r < 4; ++r) {
      const int rl = lg * 4 + r;
      const int sw = (rl & 7) << 3;
      #pragma unroll
      for (int a = 0; a < 32; ++a) {
        const int l = (a >> 1) * 64 + lh * 32 + (a & 1) * 16 + lr;
        pb[rl * 1024 + (l ^ sw)] = (_Float16)(acc[a][r] * inv[r]);
      }
    }
  }
  __syncthreads();

  // ---------------- Phase C: out = P @ pro (8-deep fragT batches) ----------------
  f32x4 acc2[2][4];
  #pragma unroll
  for (int mt = 0; mt < 2; ++mt)
    #pragma unroll
    for (int nt = 0; nt < 4; ++nt) acc2[mt][nt] = (f32x4){0.f, 0.f, 0.f, 0.f};

  const _Float16* pa = (const _Float16*)bufA;
  const _Float16* pbb = (const _Float16*)bufB;
  const f16x8* btw = fragT + ((size_t)(p * 16 + w * 4) * 32) * 64 + lane;
  const int kcmax2 = (((len + 31) >> 5) + 1) & ~1;  // even; P tail is zeros in LDS
  const int swp = (lr & 7) << 3;

  for (int kc = 0; kc < kcmax2; kc += 2) {
    f16x8 bf[8];
    #pragma unroll
    for (int u = 0; u < 2; ++u)
      #pragma unroll
      for (int nt = 0; nt < 4; ++nt) bf[u * 4 + nt] = btw[(nt * 32 + kc + u) * 64];
    #pragma unroll
    for (int u = 0; u < 2; ++u) {
      const int cidx = (((kc + u) * 32 + lg * 8) ^ swp) + lr * 1024;
      f16x8 a0 = *(const f16x8*)&pa[cidx];
      f16x8 a1 = *(const f16x8*)&pbb[cidx];
      #pragma unroll
      for (int nt = 0; nt < 4; ++nt) {
        acc2[0][nt] =
            __builtin_amdgcn_mfma_f32_16x16x32_f16(a0, bf[u * 4 + nt], acc2[0][nt], 0, 0, 0);
        acc2[1][nt] =
            __builtin_amdgcn_mfma_f32_16x16x32_f16(a1, bf[u * 4 + nt], acc2[1][nt], 0, 0, 0);
      }
    }
  }

  #pragma unroll
  for (int mt = 0; mt < 2; ++mt) {
    #pragma unroll
    for (int nt = 0; nt < 4; ++nt) {
      #pragma unroll
      for (int r = 0; r < 4; ++r) {
        __builtin_nontemporal_store(
            acc2[mt][nt][r],
            &out[((size_t)p * TERM_NUM + t0 + mt * 16 + lg * 4 + r) * HID + w * 64 + nt * 16 + lr]);
      }
    }
  }

  // ---------------- coalesced attn writeback (full lines, NT, len-clipped) --------
  // thread t: row = t>>3 (0..31), cols (t&7)*8 + j*64; live chunks read LDS, dead
  // chunks store zeros (P beyond len is exactly 0).
  {
    const int row = tid >> 3;
    const int rl = row & 15;
    const int sw = (rl & 7) << 3;
    const _Float16* pb = (const _Float16*)((row < 16) ? bufA : bufB);
    float* arow = attn + ((size_t)(p * TERM_NUM + t0 + row)) * MAX_LEN;
    const int c0 = (tid & 7) * 8;
    const f32x4 zz = {0.f, 0.f, 0.f, 0.f};
    #pragma unroll
    for (int j = 0; j < 16; ++j) {
      const int l0 = c0 + j * 64;
      if (j < nchunks) {
        f16x8 v = *(const f16x8*)&pb[rl * 1024 + (l0 ^ sw)];
        f32x4 o0 = {(float)v[0], (float)v[1], (float)v[2], (float)v[3]};
        f32x4 o1 = {(float)v[4], (float)v[5], (float)v[6], (float)v[7]};
        __builtin_nontemporal_store(o0, (f32x4*)(arow + l0));
        __builtin_nontemporal_store(o1, (f32x4*)(arow + l0 + 4));
      } else {
        __builtin_nontemporal_store(zz, (f32x4*)(arow + l0));
        __builtin_nontemporal_store(zz, (f32x4*)(arow + l0 + 4));
      }
    }
  }
}

extern "C" void kernel_launch(void* const* d_in, const int* in_sizes, int n_in,
                              void* d_out, int out_size, void* d_ws, size_t ws_size,
                              hipStream_t stream) {
  const float* term = (const float*)d_in[0];
  const float* pro  = (const float*)d_in[1];
  const int*   lens = (const int*)d_in[2];

  float* out  = (float*)d_out;
  float* attn = out + (size_t)PRO_NUM * TERM_NUM * HID;

  char*  img   = (char*)d_ws;                                    // 33.55 MB
  f16x8* fragT = (f16x8*)(img + (size_t)PRO_NUM * 16 * 32768);   // 33.55 MB

  k_prep<<<dim3(16, PRO_NUM), 256, 0, stream>>>(pro, img, fragT);
  k_fused<<<dim3(PRO_NUM * (TERM_NUM / 32)), 256, 0, stream>>>(term, img, fragT, lens, attn, out);
}

// Round 14
// 148.230 us; speedup vs baseline: 1.0372x; 1.0372x over previous
//
#include <hip/hip_runtime.h>
#include <stdint.h>

#define PRO_NUM 64
#define TERM_NUM 512
#define MAX_LEN 1024
#define HID 256

typedef _Float16 f16x8 __attribute__((ext_vector_type(8)));
typedef float f32x4 __attribute__((ext_vector_type(4)));

__device__ __forceinline__ f16x8 cvt8(const float* __restrict__ s) {
  float4 a = *(const float4*)s;
  float4 b = *(const float4*)(s + 4);
  f16x8 r = {(_Float16)a.x, (_Float16)a.y, (_Float16)a.z, (_Float16)a.w,
             (_Float16)b.x, (_Float16)b.y, (_Float16)b.z, (_Float16)b.w};
  return r;
}

// async global->LDS, 16B per lane; lds base must be wave-uniform (HW adds lane*16)
__device__ __forceinline__ void gll16(const void* g, void* l) {
  __builtin_amdgcn_global_load_lds(
      (const __attribute__((address_space(1))) uint32_t*)g,
      (__attribute__((address_space(3))) uint32_t*)l, 16, 0, 0);
}

// K1: pro f32 -> (a) img: per-(p,64-l-chunk) 32KB swizzled LDS images of pro_h
//                (byte(l,h8) = l*512 + ((h8*16) ^ ((l&7)<<4)), h8 = h/8)
//                (b) fragT: PV B-operand fragments.
__global__ __launch_bounds__(256) void k_prep(const float* __restrict__ pro,
                                              char* __restrict__ img,
                                              f16x8* __restrict__ fragT) {
  __shared__ _Float16 ldsA[64][264];
  const int p = blockIdx.y;
  const int lc = blockIdx.x;
  const int tid = threadIdx.x;

  const float* src = pro + ((size_t)p * MAX_LEN + lc * 64) * HID;
  #pragma unroll
  for (int j = 0; j < 16; ++j) {
    int idx = j * 1024 + tid * 4;
    int l = idx >> 8, h = idx & 255;
    float4 v = *(const float4*)(src + idx);
    ldsA[l][h + 0] = (_Float16)v.x;
    ldsA[l][h + 1] = (_Float16)v.y;
    ldsA[l][h + 2] = (_Float16)v.z;
    ldsA[l][h + 3] = (_Float16)v.w;
  }
  __syncthreads();

  // (a) swizzled image
  {
    char* dst = img + ((size_t)(p * 16 + lc)) * 32768;
    const int h8 = tid & 31;
    const int l0 = tid >> 5;  // 0..7
    #pragma unroll
    for (int j = 0; j < 8; ++j) {
      const int l = j * 8 + l0;
      f16x8 v = *(const f16x8*)&ldsA[l][h8 * 8];
      *(f16x8*)(dst + l * 512 + ((h8 * 16) ^ ((l & 7) << 4))) = v;
    }
  }

  // (b) fragT
  const int w = tid >> 6;
  const int lane = tid & 63;
  const int lr = lane & 15;
  const int lg = lane >> 4;
  #pragma unroll
  for (int hh = 0; hh < 4; ++hh) {
    const int H = w * 4 + hh;
    #pragma unroll
    for (int k2 = 0; k2 < 2; ++k2) {
      const int kc = lc * 2 + k2;
      const int lloc = k2 * 32 + lg * 8;
      f16x8 v;
      #pragma unroll
      for (int i = 0; i < 8; ++i) v[i] = ldsA[lloc + i][H * 16 + lr];
      fragT[((size_t)(p * 16 + H) * 32 + kc) * 64 + lane] = v;
    }
  }
}

// K2 (fused): block = (p, 32 terms), 4 waves. On-device LPT schedule:
//   bid&7 = XCD slot; p's are snake-assigned to XCDs by len-rank (balanced sums),
//   issued longest-first within each XCD; all 16 t-tiles of a p share one XCD
//   (img[p] L2 reuse, R12-proven). Phase A: len-clipped chunk loop, double-buffered
//   global_load_lds. Softmax -> P to LDS (f16 swizzled). Phase C: PV from LDS P +
//   fragT. Finally: coalesced NT attn writeback, len-clipped, zero-fill tail.
__global__ __launch_bounds__(256) void k_fused(
    const float* __restrict__ term, const char* __restrict__ img,
    const f16x8* __restrict__ fragT, const int* __restrict__ lens,
    float* __restrict__ attn, float* __restrict__ out) {
  __shared__ __align__(16) char bufA[32768];  // chunk stage (even) / P rows 0-15
  __shared__ __align__(16) char bufB[32768];  // chunk stage (odd)  / P rows 16-31
  __shared__ float rmx[4][16];
  __shared__ float rsm[4][16];
  __shared__ int len_s[64];
  __shared__ int p_sh;

  const int bid = blockIdx.x;
  const int xcd = bid & 7;
  const int idx = bid >> 3;    // 0..127 within-XCD slot
  const int round = idx >> 4;  // 0..7  (issue order within XCD)
  const int tt = idx & 15;     // t-tile of this p

  const int tid = threadIdx.x;

  // --- on-device LPT lookup: p = p whose len-rank == round*8 + snake(xcd,round) ---
  if (tid < 64) len_s[tid] = lens[tid];
  __syncthreads();
  if (tid < 64) {
    const int L = len_s[tid];
    int rank = 0;
    #pragma unroll 8
    for (int j = 0; j < 64; ++j) {
      const int Lj = len_s[j];
      rank += (Lj > L) || (Lj == L && j < tid);
    }
    const int target = round * 8 + ((round & 1) ? (7 - xcd) : xcd);
    if (rank == target) p_sh = tid;
  }
  __syncthreads();
  const int p = p_sh;
  const int t0 = tt * 32;
  const int len = len_s[p];

  const int w = tid >> 6;
  const int lane = tid & 63;
  const int lr = lane & 15;
  const int lg = lane >> 4;
  const int mw = w & 1;   // m-tile owned by this wave
  const int lh = w >> 1;  // l-half within each chunk
  const int nchunks = (len + 63) >> 6;  // 1..16, wave-uniform

  // A fragments (term rows t0+mw*16+lr)
  f16x8 af[8];
  {
    const float* trow = term + (size_t)(t0 + mw * 16 + lr) * HID + lg * 8;
    #pragma unroll
    for (int kk = 0; kk < 8; ++kk) af[kk] = cvt8(trow + kk * 32);
  }

  f32x4 acc[32];
  #pragma unroll
  for (int i = 0; i < 32; ++i) acc[i] = (f32x4){0.f, 0.f, 0.f, 0.f};

  const char* imgp = img + ((size_t)p * 16) * 32768 + w * 1024 + lane * 16;
  char* stA = bufA + w * 1024;
  char* stB = bufB + w * 1024;

  // prologue: stage chunk 0 (len >= 1 always)
  #pragma unroll
  for (int r = 0; r < 8; ++r) gll16(imgp + r * 4096, stA + r * 4096);
  __syncthreads();

  const int swk = (lr & 7) << 4;
  #pragma unroll
  for (int c = 0; c < 16; ++c) {
    if (c + 1 < nchunks) {  // stage next live chunk
      const char* src = imgp + (size_t)(c + 1) * 32768;
      char* dst = (c & 1) ? stA : stB;
      #pragma unroll
      for (int r = 0; r < 8; ++r) gll16(src + r * 4096, dst + r * 4096);
    }
    if (c < nchunks) {  // compute live chunk (wave-uniform)
      const char* cur = (c & 1) ? bufB : bufA;
      #pragma unroll
      for (int j = 0; j < 2; ++j) {
        const int lt = lh * 2 + j;
        const char* rowp = cur + (lt * 16 + lr) * 512;
        f16x8 bf[8];
        #pragma unroll
        for (int kk = 0; kk < 8; ++kk)
          bf[kk] = *(const f16x8*)(rowp + ((kk * 64 + lg * 16) ^ swk));
        #pragma unroll
        for (int kk = 0; kk < 8; ++kk)
          acc[c * 2 + j] =
              __builtin_amdgcn_mfma_f32_16x16x32_f16(af[kk], bf[kk], acc[c * 2 + j], 0, 0, 0);
      }
    }
    __syncthreads();  // uniform barrier every iteration
  }

  // ---------------- softmax ----------------
  float rmax[4] = {-INFINITY, -INFINITY, -INFINITY, -INFINITY};
  #pragma unroll
  for (int a = 0; a < 32; ++a) {
    const int l = (a >> 1) * 64 + lh * 32 + (a & 1) * 16 + lr;
    #pragma unroll
    for (int r = 0; r < 4; ++r) {
      float s = (l < len) ? acc[a][r] : -INFINITY;
      acc[a][r] = s;
      rmax[r] = fmaxf(rmax[r], s);
    }
  }
  #pragma unroll
  for (int m = 1; m < 16; m <<= 1) {
    #pragma unroll
    for (int r = 0; r < 4; ++r) rmax[r] = fmaxf(rmax[r], __shfl_xor(rmax[r], m));
  }
  if (lr == 0) {
    #pragma unroll
    for (int r = 0; r < 4; ++r) rmx[w][lg * 4 + r] = rmax[r];
  }
  __syncthreads();
  float fm[4];
  #pragma unroll
  for (int r = 0; r < 4; ++r) {
    const int rl = lg * 4 + r;
    fm[r] = fmaxf(rmx[mw][rl], rmx[2 + mw][rl]);
  }
  float rsum[4] = {0.f, 0.f, 0.f, 0.f};
  #pragma unroll
  for (int a = 0; a < 32; ++a) {
    #pragma unroll
    for (int r = 0; r < 4; ++r) {
      float e = __expf(acc[a][r] - fm[r]);  // masked -> 0
      acc[a][r] = e;
      rsum[r] += e;
    }
  }
  #pragma unroll
  for (int m = 1; m < 16; m <<= 1) {
    #pragma unroll
    for (int r = 0; r < 4; ++r) rsum[r] += __shfl_xor(rsum[r], m);
  }
  if (lr == 0) {
    #pragma unroll
    for (int r = 0; r < 4; ++r) rsm[w][lg * 4 + r] = rsum[r];
  }
  __syncthreads();
  float inv[4];
  #pragma unroll
  for (int r = 0; r < 4; ++r) {
    const int rl = lg * 4 + r;
    inv[r] = 1.0f / (rsm[mw][rl] + rsm[2 + mw][rl]);
  }

  // P -> LDS only (f16, col ^ ((row&7)<<3)); bufA rows 0-15, bufB rows 16-31
  {
    _Float16* pb = (_Float16*)(mw ? bufB : bufA);
    #pragma unroll
    for (int r = 0; r < 4; ++r) {
      const int rl = lg * 4 + r;
      const int sw = (rl & 7) << 3;
      #pragma unroll
      for (int a = 0; a < 32; ++a) {
        const int l = (a >> 1) * 64 + lh * 32 + (a & 1) * 16 + lr;
        pb[rl * 1024 + (l ^ sw)] = (_Float16)(acc[a][r] * inv[r]);
      }
    }
  }
  __syncthreads();

  // ---------------- Phase C: out = P @ pro (8-deep fragT batches) ----------------
  f32x4 acc2[2][4];
  #pragma unroll
  for (int mt = 0; mt < 2; ++mt)
    #pragma unroll
    for (int nt = 0; nt < 4; ++nt) acc2[mt][nt] = (f32x4){0.f, 0.f, 0.f, 0.f};

  const _Float16* pa = (const _Float16*)bufA;
  const _Float16* pbb = (const _Float16*)bufB;
  const f16x8* btw = fragT + ((size_t)(p * 16 + w * 4) * 32) * 64 + lane;
  const int kcmax2 = (((len + 31) >> 5) + 1) & ~1;  // even; P tail is zeros in LDS
  const int swp = (lr & 7) << 3;

  for (int kc = 0; kc < kcmax2; kc += 2) {
    f16x8 bf[8];
    #pragma unroll
    for (int u = 0; u < 2; ++u)
      #pragma unroll
      for (int nt = 0; nt < 4; ++nt) bf[u * 4 + nt] = btw[(nt * 32 + kc + u) * 64];
    #pragma unroll
    for (int u = 0; u < 2; ++u) {
      const int cidx = (((kc + u) * 32 + lg * 8) ^ swp) + lr * 1024;
      f16x8 a0 = *(const f16x8*)&pa[cidx];
      f16x8 a1 = *(const f16x8*)&pbb[cidx];
      #pragma unroll
      for (int nt = 0; nt < 4; ++nt) {
        acc2[0][nt] =
            __builtin_amdgcn_mfma_f32_16x16x32_f16(a0, bf[u * 4 + nt], acc2[0][nt], 0, 0, 0);
        acc2[1][nt] =
            __builtin_amdgcn_mfma_f32_16x16x32_f16(a1, bf[u * 4 + nt], acc2[1][nt], 0, 0, 0);
      }
    }
  }

  #pragma unroll
  for (int mt = 0; mt < 2; ++mt) {
    #pragma unroll
    for (int nt = 0; nt < 4; ++nt) {
      #pragma unroll
      for (int r = 0; r < 4; ++r) {
        __builtin_nontemporal_store(
            acc2[mt][nt][r],
            &out[((size_t)p * TERM_NUM + t0 + mt * 16 + lg * 4 + r) * HID + w * 64 + nt * 16 + lr]);
      }
    }
  }

  // ---------------- coalesced attn writeback (full lines, NT, len-clipped) --------
  {
    const int row = tid >> 3;
    const int rl = row & 15;
    const int sw = (rl & 7) << 3;
    const _Float16* pb = (const _Float16*)((row < 16) ? bufA : bufB);
    float* arow = attn + ((size_t)(p * TERM_NUM + t0 + row)) * MAX_LEN;
    const int c0 = (tid & 7) * 8;
    const f32x4 zz = {0.f, 0.f, 0.f, 0.f};
    #pragma unroll
    for (int j = 0; j < 16; ++j) {
      const int l0 = c0 + j * 64;
      if (j < nchunks) {
        f16x8 v = *(const f16x8*)&pb[rl * 1024 + (l0 ^ sw)];
        f32x4 o0 = {(float)v[0], (float)v[1], (float)v[2], (float)v[3]};
        f32x4 o1 = {(float)v[4], (float)v[5], (float)v[6], (float)v[7]};
        __builtin_nontemporal_store(o0, (f32x4*)(arow + l0));
        __builtin_nontemporal_store(o1, (f32x4*)(arow + l0 + 4));
      } else {
        __builtin_nontemporal_store(zz, (f32x4*)(arow + l0));
        __builtin_nontemporal_store(zz, (f32x4*)(arow + l0 + 4));
      }
    }
  }
}

extern "C" void kernel_launch(void* const* d_in, const int* in_sizes, int n_in,
                              void* d_out, int out_size, void* d_ws, size_t ws_size,
                              hipStream_t stream) {
  const float* term = (const float*)d_in[0];
  const float* pro  = (const float*)d_in[1];
  const int*   lens = (const int*)d_in[2];

  float* out  = (float*)d_out;
  float* attn = out + (size_t)PRO_NUM * TERM_NUM * HID;

  char*  img   = (char*)d_ws;                                    // 33.55 MB
  f16x8* fragT = (f16x8*)(img + (size_t)PRO_NUM * 16 * 32768);   // 33.55 MB

  k_prep<<<dim3(16, PRO_NUM), 256, 0, stream>>>(pro, img, fragT);
  k_fused<<<dim3(PRO_NUM * (TERM_NUM / 32)), 256, 0, stream>>>(term, img, fragT, lens, attn, out);
}